// Round 4
// baseline (436.731 us; speedup 1.0000x reference)
//
#include <hip/hip_runtime.h>

// ---- problem constants ----
#define NN 25000          // nodes
#define NE 400000         // edges
#define NGR 64            // graphs
#define CHUNK 12500       // nodes per xw-buffer chunk
// IN=HID=OUT=16, EF=8, EH=64, NH=128, NC=10
#define EPS 1e-5f

// ---- workspace layout (floats) ----
static const size_t OFS_XWBUF  = 0;          // CHUNK*1024 = 12,800,000
static const size_t OFS_H1     = 0;          // N*16 (alias; xwbuf dead when k3 writes)
static const size_t OFS_XB2    = 12800000;   // N*16
static const size_t OFS_MSG    = 13200000;   // NE*16 = 6,400,000 (per-edge messages, CSC order)
static const size_t OFS_STATS  = 19600000;   // 2048
static const size_t OFS_ELIST  = 19625600;   // NE (int)  edge id in CSR order
static const size_t OFS_POSL   = 20025600;   // NE (int)  CSC slot in CSR order
static const size_t OFS_OFF    = 20425600;   // 25600 (int) CSR offsets
static const size_t OFS_CSCOFF = 20451200;   // 25600 (int) CSC offsets
static const size_t OFS_OUTC   = 20476800;   // 25600 (int) src hist / cursor
static const size_t OFS_INC    = 20502400;   // 25600 (int) dst hist / cursor
// total 20,528,000 floats = 82.1 MB
// stats: [0]sum1 [16]sumsq1 [32]scale1 [48]shift1 [64]sum2 [80]sumsq2
//        [96]scale2 [112]shift2 [128]gsum_raw(64*16) [1152]gcnt(64)

__device__ __forceinline__ void atomAddF(float* p, float v) {
  unsafeAtomicAdd(p, v);
}

// ---------------- CSR+CSC build ----------------
__global__ __launch_bounds__(256) void k0_hist(const int* __restrict__ esrc,
    const int* __restrict__ edst, int* __restrict__ outc, int* __restrict__ inc) {
  for (int e = blockIdx.x*blockDim.x + threadIdx.x; e < NE; e += gridDim.x*blockDim.x) {
    atomicAdd(&outc[esrc[e]], 1);
    atomicAdd(&inc[edst[e]], 1);
  }
}

__global__ __launch_bounds__(1024) void k0_scan(int* __restrict__ outc, int* __restrict__ off,
    int* __restrict__ inc, int* __restrict__ cscoff) {
  __shared__ int ps[1024];
  const int t = threadIdx.x;
  const int base = t * 25;            // 1024*25 = 25600 >= 25001
  // scan 1: outc -> off (CSR)
  int s = 0;
  for (int k = 0; k < 25; ++k) { int i = base + k; if (i < NN) s += outc[i]; }
  ps[t] = s; __syncthreads();
  for (int st = 1; st < 1024; st <<= 1) {
    int v = (t >= st) ? ps[t - st] : 0;
    __syncthreads(); ps[t] += v; __syncthreads();
  }
  int run = (t > 0) ? ps[t-1] : 0;
  for (int k = 0; k < 25; ++k) {
    int i = base + k;
    if (i < NN)       { off[i] = run; run += outc[i]; outc[i] = 0; }
    else if (i == NN) { off[i] = run; }
  }
  __syncthreads();
  // scan 2: inc -> cscoff (CSC)
  s = 0;
  for (int k = 0; k < 25; ++k) { int i = base + k; if (i < NN) s += inc[i]; }
  ps[t] = s; __syncthreads();
  for (int st = 1; st < 1024; st <<= 1) {
    int v = (t >= st) ? ps[t - st] : 0;
    __syncthreads(); ps[t] += v; __syncthreads();
  }
  run = (t > 0) ? ps[t-1] : 0;
  for (int k = 0; k < 25; ++k) {
    int i = base + k;
    if (i < NN)       { cscoff[i] = run; run += inc[i]; inc[i] = 0; }
    else if (i == NN) { cscoff[i] = run; }
  }
}

__global__ __launch_bounds__(256) void k0_fill(const int* __restrict__ esrc,
    const int* __restrict__ edst, int* __restrict__ curs, int* __restrict__ curd,
    const int* __restrict__ off, const int* __restrict__ cscoff,
    int* __restrict__ elist, int* __restrict__ posl) {
  for (int e = blockIdx.x*blockDim.x + threadIdx.x; e < NE; e += gridDim.x*blockDim.x) {
    const int s = esrc[e], d = edst[e];
    const int c1 = atomicAdd(&curs[s], 1);
    const int c2 = atomicAdd(&curd[d], 1);
    const int slot = off[s] + c1;
    elist[slot] = e;
    posl[slot] = cscoff[d] + c2;
  }
}

// ---------------- K1: per-node weight precompute (chunked) ----------------
__global__ __launch_bounds__(256) void k1_xw(const float* __restrict__ x,
    const float* __restrict__ w2, const float* __restrict__ b2,
    float* __restrict__ xwbuf, float* __restrict__ xb2, int n0, int n1) {
  __shared__ float xs[16][17];
  const int t = threadIdx.x;
  const int h = t >> 2, og = (t & 3) * 4;
  const int nbase = n0 + blockIdx.x * 16;
  if (nbase >= n1) return;
  {
    const int n = nbase + (t >> 4), i = t & 15;
    xs[t >> 4][i] = (n < n1) ? x[(size_t)n*16 + i] : 0.f;
  }
  __syncthreads();
  float4 acc[16];
  #pragma unroll
  for (int n = 0; n < 16; ++n) acc[n] = make_float4(0.f,0.f,0.f,0.f);
  #pragma unroll
  for (int i = 0; i < 16; ++i) {
    const float4 w = *reinterpret_cast<const float4*>(&w2[h*256 + i*16 + og]);
    #pragma unroll
    for (int n = 0; n < 16; ++n) {
      const float xv = xs[n][i];
      acc[n].x += xv*w.x; acc[n].y += xv*w.y; acc[n].z += xv*w.z; acc[n].w += xv*w.w;
    }
  }
  #pragma unroll
  for (int n = 0; n < 16; ++n) {
    const int nn = nbase + n;
    if (nn < n1)
      *reinterpret_cast<float4*>(&xwbuf[(size_t)(nn - n0)*1024 + h*16 + og]) = acc[n];
  }
  {
    const int n = nbase + (t >> 4), o = t & 15;
    if (n < n1) {
      float s = 0.f;
      #pragma unroll
      for (int i = 0; i < 16; ++i) s += xs[t >> 4][i] * b2[i*16 + o];
      xb2[(size_t)n*16 + o] = s;
    }
  }
}

// ---------------- K2: layer-1 edge pass, CSR-by-src, plain stores to CSC slots ----------------
__global__ __launch_bounds__(256) void k2_csr(const float* __restrict__ ea,
    const float* __restrict__ w1, const float* __restrict__ b1,
    const float* __restrict__ xwbuf, const float* __restrict__ xb2,
    const int* __restrict__ off, const int* __restrict__ elist,
    const int* __restrict__ posl, float* __restrict__ msg, int n0, int n1) {
  __shared__ float w1s[512];
  __shared__ float b1s[64];
  __shared__ float xwS[4][1024];
  __shared__ float rs[4][16][68];
  for (int idx = threadIdx.x; idx < 512; idx += 256) w1s[idx] = w1[idx];
  if (threadIdx.x < 64) b1s[threadIdx.x] = b1[threadIdx.x];
  __syncthreads();
  const int lane = threadIdx.x & 63, wl = threadIdx.x >> 6;
  const int el = lane >> 2, q = lane & 3;
  const int gw = blockIdx.x*4 + wl, nw = gridDim.x*4;
  float* xw = xwS[wl];
  float (*rsw)[68] = rs[wl];

  for (int n = n0 + gw; n < n1; n += nw) {
    const int st = off[n];
    const int deg = off[n+1] - st;
    if (deg == 0) continue;
    const float4* src = reinterpret_cast<const float4*>(&xwbuf[(size_t)(n - n0)*1024]);
    #pragma unroll
    for (int j = 0; j < 4; ++j) {
      const float4 v = src[j*64 + lane];
      *reinterpret_cast<float4*>(&xw[j*256 + lane*4]) = v;
    }
    const float4 mb = *reinterpret_cast<const float4*>(&xb2[(size_t)n*16 + q*4]);
    __builtin_amdgcn_wave_barrier();

    for (int j0 = 0; j0 < deg; j0 += 16) {
      const int jj = j0 + el;
      const bool act = (jj < deg);
      const int slot = st + (act ? jj : 0);
      const int e = elist[slot];
      const int pe = posl[slot];
      const float4 ea0 = *reinterpret_cast<const float4*>(&ea[(size_t)e*8]);
      const float4 ea1 = *reinterpret_cast<const float4*>(&ea[(size_t)e*8 + 4]);
      const float eav[8] = {ea0.x, ea0.y, ea0.z, ea0.w, ea1.x, ea1.y, ea1.z, ea1.w};
      #pragma unroll
      for (int g = 0; g < 4; ++g) {
        float4 r4 = *reinterpret_cast<const float4*>(&b1s[q*16 + g*4]);
        #pragma unroll
        for (int f = 0; f < 8; ++f) {
          const float4 wv = *reinterpret_cast<const float4*>(&w1s[f*64 + q*16 + g*4]);
          r4.x += eav[f]*wv.x; r4.y += eav[f]*wv.y;
          r4.z += eav[f]*wv.z; r4.w += eav[f]*wv.w;
        }
        r4.x = fmaxf(r4.x, 0.f); r4.y = fmaxf(r4.y, 0.f);
        r4.z = fmaxf(r4.z, 0.f); r4.w = fmaxf(r4.w, 0.f);
        *reinterpret_cast<float4*>(&rsw[el][q*16 + g*4]) = r4;
      }
      __builtin_amdgcn_wave_barrier();
      float4 m = mb;
      #pragma unroll
      for (int h0 = 0; h0 < 16; ++h0) {
        const float4 rv = *reinterpret_cast<const float4*>(&rsw[el][h0*4]);
        const float4 x0 = *reinterpret_cast<const float4*>(&xw[(h0*4+0)*16 + q*4]);
        const float4 x1 = *reinterpret_cast<const float4*>(&xw[(h0*4+1)*16 + q*4]);
        const float4 x2 = *reinterpret_cast<const float4*>(&xw[(h0*4+2)*16 + q*4]);
        const float4 x3 = *reinterpret_cast<const float4*>(&xw[(h0*4+3)*16 + q*4]);
        m.x += rv.x*x0.x + rv.y*x1.x + rv.z*x2.x + rv.w*x3.x;
        m.y += rv.x*x0.y + rv.y*x1.y + rv.z*x2.y + rv.w*x3.y;
        m.z += rv.x*x0.z + rv.y*x1.z + rv.z*x2.z + rv.w*x3.z;
        m.w += rv.x*x0.w + rv.y*x1.w + rv.z*x2.w + rv.w*x3.w;
      }
      if (act)
        *reinterpret_cast<float4*>(&msg[(size_t)pe*16 + q*4]) = m;
      __builtin_amdgcn_wave_barrier();
    }
  }
}

// ---------------- K3: reduce msg slices + x@root1 + bias1; BN1 stats ----------------
__global__ __launch_bounds__(256) void k3_node1(const float* __restrict__ x,
    const float* __restrict__ root1, const float* __restrict__ bias1,
    const float* __restrict__ msg, const int* __restrict__ cscoff,
    float* __restrict__ h1, float* __restrict__ stats) {
  __shared__ float rt[256];
  __shared__ float red[2][16][17];
  rt[threadIdx.x] = root1[threadIdx.x];
  const int o = threadIdx.x & 15, nl = threadIdx.x >> 4;
  const float bo = bias1[o];
  float s1 = 0.f, s2 = 0.f;
  __syncthreads();
  for (int n = blockIdx.x*16 + nl; n < NN; n += gridDim.x*16) {
    const int b0 = cscoff[n];
    const int deg = cscoff[n+1] - b0;
    float sm = 0.f;
    for (int j = 0; j < deg; ++j) sm += msg[(size_t)(b0 + j)*16 + o];
    float acc = bo;
    #pragma unroll
    for (int i = 0; i < 16; ++i) acc += x[(size_t)n*16 + i] * rt[i*16 + o];
    acc += sm / (float)((deg > 0) ? deg : 1);
    h1[(size_t)n*16 + o] = acc;
    s1 += acc; s2 += acc*acc;
  }
  red[0][nl][o] = s1; red[1][nl][o] = s2;
  __syncthreads();
  for (int step = 8; step > 0; step >>= 1) {
    if (nl < step) {
      red[0][nl][o] += red[0][nl+step][o];
      red[1][nl][o] += red[1][nl+step][o];
    }
    __syncthreads();
  }
  if (nl == 0) { atomAddF(&stats[o], red[0][0][o]); atomAddF(&stats[16+o], red[1][0][o]); }
}

__global__ void k4_fin1(const float* __restrict__ g, const float* __restrict__ b,
                        float* __restrict__ stats) {
  const int o = threadIdx.x;
  if (o < 16) {
    const float mean = stats[o] / (float)NN;
    const float var  = stats[16+o] / (float)NN - mean*mean;
    const float sc   = g[o] * rsqrtf(var + EPS);
    stats[32+o] = sc;
    stats[48+o] = b[o] - mean*sc;
  }
}

// ---------------- K6: layer-2 edge pass, plain stores to CSC slots ----------------
__global__ __launch_bounds__(256) void k6_csr(const float* __restrict__ ea,
    const float* __restrict__ h1, const float* __restrict__ stats,
    const float* __restrict__ w, const float* __restrict__ bvec,
    const int* __restrict__ off, const int* __restrict__ elist,
    const int* __restrict__ posl, float* __restrict__ msg) {
  __shared__ float ws2[2048];
  __shared__ float bs2[256];
  __shared__ float hwS[4][128];
  __shared__ float hbS[4][32];   // [0..15] hbn, [16..31] hb
  for (int idx = threadIdx.x; idx < 2048; idx += 256) ws2[idx] = w[idx];
  bs2[threadIdx.x] = bvec[threadIdx.x];
  __syncthreads();
  const int lane = threadIdx.x & 63, wl = threadIdx.x >> 6;
  const int el = lane >> 2, q = lane & 3;
  const int f = lane >> 3, o2 = (lane & 7) * 2;
  const int gw = blockIdx.x*4 + wl, nw = gridDim.x*4;
  for (int n = gw; n < NN; n += nw) {
    const int st = off[n];
    const int deg = off[n+1] - st;
    if (deg == 0) continue;
    if (lane < 16)
      hbS[wl][lane] = h1[(size_t)n*16 + lane]*stats[32+lane] + stats[48+lane];
    __builtin_amdgcn_wave_barrier();
    float a0 = 0.f, a1 = 0.f;
    #pragma unroll
    for (int i = 0; i < 16; ++i) {
      const float hv = hbS[wl][i];
      a0 += hv * ws2[f*256 + i*16 + o2];
      a1 += hv * ws2[f*256 + i*16 + o2 + 1];
    }
    hwS[wl][f*16 + o2] = a0; hwS[wl][f*16 + o2 + 1] = a1;
    if (lane < 16) {
      float s = 0.f;
      #pragma unroll
      for (int i = 0; i < 16; ++i) s += hbS[wl][i] * bs2[i*16 + lane];
      hbS[wl][16 + lane] = s;
    }
    __builtin_amdgcn_wave_barrier();
    const float4 mb = *reinterpret_cast<const float4*>(&hbS[wl][16 + q*4]);
    for (int j0 = 0; j0 < deg; j0 += 16) {
      const int jj = j0 + el;
      const bool act = (jj < deg);
      const int slot = st + (act ? jj : 0);
      const int e = elist[slot];
      const int pe = posl[slot];
      const float4 ea0 = *reinterpret_cast<const float4*>(&ea[(size_t)e*8]);
      const float4 ea1 = *reinterpret_cast<const float4*>(&ea[(size_t)e*8 + 4]);
      const float ef[8] = {ea0.x, ea0.y, ea0.z, ea0.w, ea1.x, ea1.y, ea1.z, ea1.w};
      float4 m = mb;
      #pragma unroll
      for (int ff = 0; ff < 8; ++ff) {
        const float4 hv = *reinterpret_cast<const float4*>(&hwS[wl][ff*16 + q*4]);
        m.x += ef[ff]*hv.x; m.y += ef[ff]*hv.y; m.z += ef[ff]*hv.z; m.w += ef[ff]*hv.w;
      }
      if (act)
        *reinterpret_cast<float4*>(&msg[(size_t)pe*16 + q*4]) = m;
      __builtin_amdgcn_wave_barrier();
    }
  }
}

// ---------------- K7: reduce msg + bn1(h1)@root2 + bias2; BN2 stats + raw pooling ----------------
#define PB 98   // nodes per block; 256*98 = 25088 >= 25000
__global__ __launch_bounds__(256) void k7_node2(const float* __restrict__ h1,
    const float* __restrict__ root2, const float* __restrict__ bias2,
    const float* __restrict__ msg, const int* __restrict__ cscoff,
    const int* __restrict__ batch, float* __restrict__ stats) {
  __shared__ float rt[256];
  __shared__ float red[2][16][17];
  __shared__ float sc[16], sh[16];
  __shared__ float pool[64*17];   // [g*17 + o], col 16 = count
  rt[threadIdx.x] = root2[threadIdx.x];
  if (threadIdx.x < 16) { sc[threadIdx.x] = stats[32+threadIdx.x]; sh[threadIdx.x] = stats[48+threadIdx.x]; }
  for (int idx = threadIdx.x; idx < 64*17; idx += 256) pool[idx] = 0.f;
  const int o = threadIdx.x & 15, nl = threadIdx.x >> 4;
  const float bo = bias2[o];
  const int nstart = blockIdx.x * PB;
  const int nend = (nstart + PB < NN) ? nstart + PB : NN;
  float s1 = 0.f, s2 = 0.f;
  __syncthreads();
  for (int n = nstart + nl; n < nend; n += 16) {
    const int b0 = cscoff[n];
    const int deg = cscoff[n+1] - b0;
    float sm = 0.f;
    for (int j = 0; j < deg; ++j) sm += msg[(size_t)(b0 + j)*16 + o];
    float acc = bo;
    #pragma unroll
    for (int i = 0; i < 16; ++i) {
      const float hbn = h1[(size_t)n*16 + i]*sc[i] + sh[i];
      acc += hbn * rt[i*16 + o];
    }
    acc += sm / (float)((deg > 0) ? deg : 1);
    s1 += acc; s2 += acc*acc;
    const int g = batch[n];
    atomicAdd(&pool[g*17 + o], acc);
    if (o == 0) atomicAdd(&pool[g*17 + 16], 1.0f);
  }
  red[0][nl][o] = s1; red[1][nl][o] = s2;
  __syncthreads();
  for (int step = 8; step > 0; step >>= 1) {
    if (nl < step) {
      red[0][nl][o] += red[0][nl+step][o];
      red[1][nl][o] += red[1][nl+step][o];
    }
    __syncthreads();
  }
  if (nl == 0) { atomAddF(&stats[64+o], red[0][0][o]); atomAddF(&stats[80+o], red[1][0][o]); }
  for (int idx = threadIdx.x; idx < 64*17; idx += 256) {
    const float v = pool[idx];
    if (v != 0.f) {
      const int g = idx / 17, c = idx - g*17;
      atomAddF((c < 16) ? &stats[128 + g*16 + c] : &stats[1152 + g], v);
    }
  }
}

__global__ void k8_fin2(const float* __restrict__ g, const float* __restrict__ b,
                        float* __restrict__ stats) {
  const int o = threadIdx.x;
  if (o < 16) {
    const float mean = stats[64+o] / (float)NN;
    const float var  = stats[80+o] / (float)NN - mean*mean;
    const float sc   = g[o] * rsqrtf(var + EPS);
    stats[96+o]  = sc;
    stats[112+o] = b[o] - mean*sc;
  }
}

// ---------------- K10: graph mean (raw) -> BN2 affine -> MLP head -> log_softmax ----------------
__global__ __launch_bounds__(128) void k10_head(const float* __restrict__ stats,
    const float* __restrict__ w1, const float* __restrict__ b1,
    const float* __restrict__ w2, const float* __restrict__ b2,
    float* __restrict__ out) {
  __shared__ float gm[16];
  __shared__ float a[128];
  __shared__ float l[10];
  __shared__ float mls[2];
  const int g = blockIdx.x, j = threadIdx.x;
  if (j < 16) {
    const float cnt = fmaxf(stats[1152 + g], 1.0f);
    gm[j] = (stats[128 + g*16 + j] / cnt) * stats[96 + j] + stats[112 + j];
  }
  __syncthreads();
  float s = b1[j];
  #pragma unroll
  for (int o = 0; o < 16; ++o) s += gm[o]*w1[o*128 + j];
  a[j] = fmaxf(s, 0.f);
  __syncthreads();
  if (j < 10) {
    float t = b2[j];
    #pragma unroll 16
    for (int k = 0; k < 128; ++k) t += a[k]*w2[k*10 + j];
    l[j] = t;
  }
  __syncthreads();
  if (j == 0) {
    float m = l[0];
    for (int c = 1; c < 10; ++c) m = fmaxf(m, l[c]);
    float se = 0.f;
    for (int c = 0; c < 10; ++c) se += expf(l[c]-m);
    mls[0] = m; mls[1] = logf(se);
  }
  __syncthreads();
  if (j < 10) out[g*10 + j] = l[j] - mls[0] - mls[1];
}

extern "C" void kernel_launch(void* const* d_in, const int* in_sizes, int n_in,
                              void* d_out, int out_size, void* d_ws, size_t ws_size,
                              hipStream_t stream) {
  const float* x      = (const float*)d_in[0];
  const int*   esrc   = (const int*)  d_in[1];
  const int*   edst   = (const int*)  d_in[2];
  const float* ea     = (const float*)d_in[3];
  const int*   batch  = (const int*)  d_in[4];
  const float* en1_w1 = (const float*)d_in[5];
  const float* en1_b1 = (const float*)d_in[6];
  const float* en1_w2 = (const float*)d_in[7];
  const float* en1_b2 = (const float*)d_in[8];
  const float* root1  = (const float*)d_in[9];
  const float* bias1  = (const float*)d_in[10];
  const float* bn1_g  = (const float*)d_in[11];
  const float* bn1_b  = (const float*)d_in[12];
  const float* en2_w  = (const float*)d_in[13];
  const float* en2_b  = (const float*)d_in[14];
  const float* root2  = (const float*)d_in[15];
  const float* bias2  = (const float*)d_in[16];
  const float* bn2_g  = (const float*)d_in[17];
  const float* bn2_b  = (const float*)d_in[18];
  const float* mlp_w1 = (const float*)d_in[19];
  const float* mlp_b1 = (const float*)d_in[20];
  const float* mlp_w2 = (const float*)d_in[21];
  const float* mlp_b2 = (const float*)d_in[22];
  float* out = (float*)d_out;
  float* ws  = (float*)d_ws;

  float* xwbuf  = ws + OFS_XWBUF;
  float* xb2    = ws + OFS_XB2;
  float* msg    = ws + OFS_MSG;
  float* stats  = ws + OFS_STATS;
  float* h1     = ws + OFS_H1;
  int*   elist  = (int*)(ws + OFS_ELIST);
  int*   posl   = (int*)(ws + OFS_POSL);
  int*   off    = (int*)(ws + OFS_OFF);
  int*   cscoff = (int*)(ws + OFS_CSCOFF);
  int*   outc   = (int*)(ws + OFS_OUTC);
  int*   inc    = (int*)(ws + OFS_INC);

  hipMemsetAsync(outc,  0, 25600*sizeof(int), stream);
  hipMemsetAsync(inc,   0, 25600*sizeof(int), stream);
  hipMemsetAsync(stats, 0, 2048*sizeof(float), stream);

  // CSR + CSC build
  hipLaunchKernelGGL(k0_hist, dim3(1024), dim3(256),  0, stream, esrc, edst, outc, inc);
  hipLaunchKernelGGL(k0_scan, dim3(1),    dim3(1024), 0, stream, outc, off, inc, cscoff);
  hipLaunchKernelGGL(k0_fill, dim3(1024), dim3(256),  0, stream, esrc, edst, outc, inc,
                     off, cscoff, elist, posl);

  // layer 1, chunked over nodes
  const int nb1 = (CHUNK + 15) / 16;
  hipLaunchKernelGGL(k1_xw,  dim3(nb1),  dim3(256), 0, stream, x, en1_w2, en1_b2, xwbuf, xb2, 0, CHUNK);
  hipLaunchKernelGGL(k2_csr, dim3(1024), dim3(256), 0, stream, ea, en1_w1, en1_b1,
                     xwbuf, xb2, off, elist, posl, msg, 0, CHUNK);
  hipLaunchKernelGGL(k1_xw,  dim3(nb1),  dim3(256), 0, stream, x, en1_w2, en1_b2, xwbuf, xb2, CHUNK, NN);
  hipLaunchKernelGGL(k2_csr, dim3(1024), dim3(256), 0, stream, ea, en1_w1, en1_b1,
                     xwbuf, xb2, off, elist, posl, msg, CHUNK, NN);

  hipLaunchKernelGGL(k3_node1, dim3(256), dim3(256), 0, stream, x, root1, bias1, msg, cscoff, h1, stats);
  hipLaunchKernelGGL(k4_fin1,  dim3(1),   dim3(64),  0, stream, bn1_g, bn1_b, stats);

  // layer 2
  hipLaunchKernelGGL(k6_csr,   dim3(1024), dim3(256), 0, stream, ea, h1, stats,
                     en2_w, en2_b, off, elist, posl, msg);
  hipLaunchKernelGGL(k7_node2, dim3(256),  dim3(256), 0, stream, h1, root2, bias2, msg, cscoff,
                     batch, stats);
  hipLaunchKernelGGL(k8_fin2,  dim3(1),    dim3(64),  0, stream, bn2_g, bn2_b, stats);

  // head
  hipLaunchKernelGGL(k10_head, dim3(64),  dim3(128), 0, stream, stats, mlp_w1, mlp_b1, mlp_w2, mlp_b2, out);
}

// Round 5
// 357.876 us; speedup vs baseline: 1.2203x; 1.2203x over previous
//
#include <hip/hip_runtime.h>

// ---- problem constants ----
#define NN 25000          // nodes
#define NE 400000         // edges
#define NGR 64            // graphs
#define CHUNK 12500       // nodes per xw-buffer chunk
// IN=HID=OUT=16, EF=8, EH=64, NH=128, NC=10
#define EPS 1e-5f

// ---- workspace layout (floats) ----
static const size_t OFS_XWBUF  = 0;          // CHUNK*1024 = 12,800,000
static const size_t OFS_H1     = 0;          // N*16 (alias; xwbuf dead when k3 writes)
static const size_t OFS_XB2    = 12800000;   // N*16
static const size_t OFS_MSG    = 13200000;   // NE*16 = 6,400,000 (per-edge messages, CSC order)
static const size_t OFS_STATS  = 19600000;   // 2048
static const size_t OFS_ELIST  = 19625600;   // NE (int)  edge id in CSR order
static const size_t OFS_POSL   = 20025600;   // NE (int)  CSC slot in CSR order
static const size_t OFS_OFF    = 20425600;   // 25600 (int) CSR offsets
static const size_t OFS_CSCOFF = 20451200;   // 25600 (int) CSC offsets
static const size_t OFS_OUTC   = 20476800;   // 25600 (int) src hist / cursor
static const size_t OFS_INC    = 20502400;   // 25600 (int) dst hist / cursor
static const size_t OFS_BSUM   = 20528000;   // 512 (int) block sums/bases for scan
// total ~20,528,512 floats = 82.1 MB
// stats: [0]sum1 [16]sumsq1 [32]scale1 [48]shift1 [64]sum2 [80]sumsq2
//        [96]scale2 [112]shift2 [128]gsum_raw(64*16) [1152]gcnt(64)
// bsum: [0..99]=O sums [100..199]=I sums [200..299]=O bases [300..399]=I bases

__device__ __forceinline__ void atomAddF(float* p, float v) {
  unsafeAtomicAdd(p, v);
}

// ---------------- CSR+CSC build ----------------
__global__ __launch_bounds__(256) void k0_hist(const int* __restrict__ esrc,
    const int* __restrict__ edst, int* __restrict__ outc, int* __restrict__ inc) {
  for (int e = blockIdx.x*blockDim.x + threadIdx.x; e < NE; e += gridDim.x*blockDim.x) {
    atomicAdd(&outc[esrc[e]], 1);
    atomicAdd(&inc[edst[e]], 1);
  }
}

// scan phase A: per-block (256-node tile) sums of both histograms
__global__ __launch_bounds__(256) void k0_scanA(const int* __restrict__ outc,
    const int* __restrict__ inc, int* __restrict__ bsum) {
  __shared__ int rO[256], rI[256];
  const int t = threadIdx.x;
  const int i = blockIdx.x*256 + t;
  rO[t] = outc[i];
  rI[t] = inc[i];
  __syncthreads();
  for (int st = 128; st > 0; st >>= 1) {
    if (t < st) { rO[t] += rO[t+st]; rI[t] += rI[t+st]; }
    __syncthreads();
  }
  if (t == 0) { bsum[blockIdx.x] = rO[0]; bsum[100 + blockIdx.x] = rI[0]; }
}

// scan phase B: exclusive-scan the 100 block sums (both arrays), tiny single block
__global__ __launch_bounds__(128) void k0_scanB(int* __restrict__ bsum) {
  __shared__ int sO[128], sI[128];
  const int t = threadIdx.x;
  const int cO = (t < 100) ? bsum[t] : 0;
  const int cI = (t < 100) ? bsum[100 + t] : 0;
  sO[t] = cO; sI[t] = cI;
  __syncthreads();
  for (int st = 1; st < 128; st <<= 1) {
    const int vO = (t >= st) ? sO[t-st] : 0;
    const int vI = (t >= st) ? sI[t-st] : 0;
    __syncthreads();
    sO[t] += vO; sI[t] += vI;
    __syncthreads();
  }
  if (t < 100) { bsum[200 + t] = sO[t] - cO; bsum[300 + t] = sI[t] - cI; }
}

// scan phase C: in-block exclusive scan + base; write off/cscoff; zero cursors
__global__ __launch_bounds__(256) void k0_scanC(int* __restrict__ outc,
    int* __restrict__ inc, const int* __restrict__ bsum,
    int* __restrict__ off, int* __restrict__ cscoff) {
  __shared__ int sO[256], sI[256];
  const int t = threadIdx.x;
  const int i = blockIdx.x*256 + t;
  const int cO = outc[i];
  const int cI = inc[i];
  sO[t] = cO; sI[t] = cI;
  __syncthreads();
  for (int st = 1; st < 256; st <<= 1) {
    const int vO = (t >= st) ? sO[t-st] : 0;
    const int vI = (t >= st) ? sI[t-st] : 0;
    __syncthreads();
    sO[t] += vO; sI[t] += vI;
    __syncthreads();
  }
  if (i <= NN) {
    off[i]    = sO[t] - cO + bsum[200 + blockIdx.x];
    cscoff[i] = sI[t] - cI + bsum[300 + blockIdx.x];
  }
  outc[i] = 0;  // -> fill cursors
  inc[i]  = 0;
}

__global__ __launch_bounds__(256) void k0_fill(const int* __restrict__ esrc,
    const int* __restrict__ edst, int* __restrict__ curs, int* __restrict__ curd,
    const int* __restrict__ off, const int* __restrict__ cscoff,
    int* __restrict__ elist, int* __restrict__ posl) {
  for (int e = blockIdx.x*blockDim.x + threadIdx.x; e < NE; e += gridDim.x*blockDim.x) {
    const int s = esrc[e], d = edst[e];
    const int c1 = atomicAdd(&curs[s], 1);
    const int c2 = atomicAdd(&curd[d], 1);
    const int slot = off[s] + c1;
    elist[slot] = e;
    posl[slot] = cscoff[d] + c2;
  }
}

// ---------------- K1: per-node weight precompute (chunked) ----------------
__global__ __launch_bounds__(256) void k1_xw(const float* __restrict__ x,
    const float* __restrict__ w2, const float* __restrict__ b2,
    float* __restrict__ xwbuf, float* __restrict__ xb2, int n0, int n1) {
  __shared__ float xs[16][17];
  const int t = threadIdx.x;
  const int h = t >> 2, og = (t & 3) * 4;
  const int nbase = n0 + blockIdx.x * 16;
  if (nbase >= n1) return;
  {
    const int n = nbase + (t >> 4), i = t & 15;
    xs[t >> 4][i] = (n < n1) ? x[(size_t)n*16 + i] : 0.f;
  }
  __syncthreads();
  float4 acc[16];
  #pragma unroll
  for (int n = 0; n < 16; ++n) acc[n] = make_float4(0.f,0.f,0.f,0.f);
  #pragma unroll
  for (int i = 0; i < 16; ++i) {
    const float4 w = *reinterpret_cast<const float4*>(&w2[h*256 + i*16 + og]);
    #pragma unroll
    for (int n = 0; n < 16; ++n) {
      const float xv = xs[n][i];
      acc[n].x += xv*w.x; acc[n].y += xv*w.y; acc[n].z += xv*w.z; acc[n].w += xv*w.w;
    }
  }
  #pragma unroll
  for (int n = 0; n < 16; ++n) {
    const int nn = nbase + n;
    if (nn < n1)
      *reinterpret_cast<float4*>(&xwbuf[(size_t)(nn - n0)*1024 + h*16 + og]) = acc[n];
  }
  {
    const int n = nbase + (t >> 4), o = t & 15;
    if (n < n1) {
      float s = 0.f;
      #pragma unroll
      for (int i = 0; i < 16; ++i) s += xs[t >> 4][i] * b2[i*16 + o];
      xb2[(size_t)n*16 + o] = s;
    }
  }
}

// ---------------- K2: layer-1 edge pass, CSR-by-src, plain stores to CSC slots ----------------
__global__ __launch_bounds__(256) void k2_csr(const float* __restrict__ ea,
    const float* __restrict__ w1, const float* __restrict__ b1,
    const float* __restrict__ xwbuf, const float* __restrict__ xb2,
    const int* __restrict__ off, const int* __restrict__ elist,
    const int* __restrict__ posl, float* __restrict__ msg, int n0, int n1) {
  __shared__ float w1s[512];
  __shared__ float b1s[64];
  __shared__ float xwS[4][1024];
  __shared__ float rs[4][16][68];
  for (int idx = threadIdx.x; idx < 512; idx += 256) w1s[idx] = w1[idx];
  if (threadIdx.x < 64) b1s[threadIdx.x] = b1[threadIdx.x];
  __syncthreads();
  const int lane = threadIdx.x & 63, wl = threadIdx.x >> 6;
  const int el = lane >> 2, q = lane & 3;
  const int gw = blockIdx.x*4 + wl, nw = gridDim.x*4;
  float* xw = xwS[wl];
  float (*rsw)[68] = rs[wl];

  for (int n = n0 + gw; n < n1; n += nw) {
    const int st = off[n];
    const int deg = off[n+1] - st;
    if (deg == 0) continue;
    const float4* src = reinterpret_cast<const float4*>(&xwbuf[(size_t)(n - n0)*1024]);
    #pragma unroll
    for (int j = 0; j < 4; ++j) {
      const float4 v = src[j*64 + lane];
      *reinterpret_cast<float4*>(&xw[j*256 + lane*4]) = v;
    }
    const float4 mb = *reinterpret_cast<const float4*>(&xb2[(size_t)n*16 + q*4]);
    __builtin_amdgcn_wave_barrier();

    for (int j0 = 0; j0 < deg; j0 += 16) {
      const int jj = j0 + el;
      const bool act = (jj < deg);
      const int slot = st + (act ? jj : 0);
      const int e = elist[slot];
      const int pe = posl[slot];
      const float4 ea0 = *reinterpret_cast<const float4*>(&ea[(size_t)e*8]);
      const float4 ea1 = *reinterpret_cast<const float4*>(&ea[(size_t)e*8 + 4]);
      const float eav[8] = {ea0.x, ea0.y, ea0.z, ea0.w, ea1.x, ea1.y, ea1.z, ea1.w};
      #pragma unroll
      for (int g = 0; g < 4; ++g) {
        float4 r4 = *reinterpret_cast<const float4*>(&b1s[q*16 + g*4]);
        #pragma unroll
        for (int f = 0; f < 8; ++f) {
          const float4 wv = *reinterpret_cast<const float4*>(&w1s[f*64 + q*16 + g*4]);
          r4.x += eav[f]*wv.x; r4.y += eav[f]*wv.y;
          r4.z += eav[f]*wv.z; r4.w += eav[f]*wv.w;
        }
        r4.x = fmaxf(r4.x, 0.f); r4.y = fmaxf(r4.y, 0.f);
        r4.z = fmaxf(r4.z, 0.f); r4.w = fmaxf(r4.w, 0.f);
        *reinterpret_cast<float4*>(&rsw[el][q*16 + g*4]) = r4;
      }
      __builtin_amdgcn_wave_barrier();
      float4 m = mb;
      #pragma unroll
      for (int h0 = 0; h0 < 16; ++h0) {
        const float4 rv = *reinterpret_cast<const float4*>(&rsw[el][h0*4]);
        const float4 x0 = *reinterpret_cast<const float4*>(&xw[(h0*4+0)*16 + q*4]);
        const float4 x1 = *reinterpret_cast<const float4*>(&xw[(h0*4+1)*16 + q*4]);
        const float4 x2 = *reinterpret_cast<const float4*>(&xw[(h0*4+2)*16 + q*4]);
        const float4 x3 = *reinterpret_cast<const float4*>(&xw[(h0*4+3)*16 + q*4]);
        m.x += rv.x*x0.x + rv.y*x1.x + rv.z*x2.x + rv.w*x3.x;
        m.y += rv.x*x0.y + rv.y*x1.y + rv.z*x2.y + rv.w*x3.y;
        m.z += rv.x*x0.z + rv.y*x1.z + rv.z*x2.z + rv.w*x3.z;
        m.w += rv.x*x0.w + rv.y*x1.w + rv.z*x2.w + rv.w*x3.w;
      }
      if (act)
        *reinterpret_cast<float4*>(&msg[(size_t)pe*16 + q*4]) = m;
      __builtin_amdgcn_wave_barrier();
    }
  }
}

// ---------------- K3: reduce msg slices + x@root1 + bias1; BN1 stats ----------------
__global__ __launch_bounds__(256) void k3_node1(const float* __restrict__ x,
    const float* __restrict__ root1, const float* __restrict__ bias1,
    const float* __restrict__ msg, const int* __restrict__ cscoff,
    float* __restrict__ h1, float* __restrict__ stats) {
  __shared__ float rt[256];
  __shared__ float red[2][16][17];
  rt[threadIdx.x] = root1[threadIdx.x];
  const int o = threadIdx.x & 15, nl = threadIdx.x >> 4;
  const float bo = bias1[o];
  float s1 = 0.f, s2 = 0.f;
  __syncthreads();
  for (int n = blockIdx.x*16 + nl; n < NN; n += gridDim.x*16) {
    const int b0 = cscoff[n];
    const int deg = cscoff[n+1] - b0;
    float sm = 0.f;
    for (int j = 0; j < deg; ++j) sm += msg[(size_t)(b0 + j)*16 + o];
    float acc = bo;
    #pragma unroll
    for (int i = 0; i < 16; ++i) acc += x[(size_t)n*16 + i] * rt[i*16 + o];
    acc += sm / (float)((deg > 0) ? deg : 1);
    h1[(size_t)n*16 + o] = acc;
    s1 += acc; s2 += acc*acc;
  }
  red[0][nl][o] = s1; red[1][nl][o] = s2;
  __syncthreads();
  for (int step = 8; step > 0; step >>= 1) {
    if (nl < step) {
      red[0][nl][o] += red[0][nl+step][o];
      red[1][nl][o] += red[1][nl+step][o];
    }
    __syncthreads();
  }
  if (nl == 0) { atomAddF(&stats[o], red[0][0][o]); atomAddF(&stats[16+o], red[1][0][o]); }
}

__global__ void k4_fin1(const float* __restrict__ g, const float* __restrict__ b,
                        float* __restrict__ stats) {
  const int o = threadIdx.x;
  if (o < 16) {
    const float mean = stats[o] / (float)NN;
    const float var  = stats[16+o] / (float)NN - mean*mean;
    const float sc   = g[o] * rsqrtf(var + EPS);
    stats[32+o] = sc;
    stats[48+o] = b[o] - mean*sc;
  }
}

// ---------------- K6: layer-2 edge pass, plain stores to CSC slots ----------------
__global__ __launch_bounds__(256) void k6_csr(const float* __restrict__ ea,
    const float* __restrict__ h1, const float* __restrict__ stats,
    const float* __restrict__ w, const float* __restrict__ bvec,
    const int* __restrict__ off, const int* __restrict__ elist,
    const int* __restrict__ posl, float* __restrict__ msg) {
  __shared__ float ws2[2048];
  __shared__ float bs2[256];
  __shared__ float hwS[4][128];
  __shared__ float hbS[4][32];   // [0..15] hbn, [16..31] hb
  for (int idx = threadIdx.x; idx < 2048; idx += 256) ws2[idx] = w[idx];
  bs2[threadIdx.x] = bvec[threadIdx.x];
  __syncthreads();
  const int lane = threadIdx.x & 63, wl = threadIdx.x >> 6;
  const int el = lane >> 2, q = lane & 3;
  const int f = lane >> 3, o2 = (lane & 7) * 2;
  const int gw = blockIdx.x*4 + wl, nw = gridDim.x*4;
  for (int n = gw; n < NN; n += nw) {
    const int st = off[n];
    const int deg = off[n+1] - st;
    if (deg == 0) continue;
    if (lane < 16)
      hbS[wl][lane] = h1[(size_t)n*16 + lane]*stats[32+lane] + stats[48+lane];
    __builtin_amdgcn_wave_barrier();
    float a0 = 0.f, a1 = 0.f;
    #pragma unroll
    for (int i = 0; i < 16; ++i) {
      const float hv = hbS[wl][i];
      a0 += hv * ws2[f*256 + i*16 + o2];
      a1 += hv * ws2[f*256 + i*16 + o2 + 1];
    }
    hwS[wl][f*16 + o2] = a0; hwS[wl][f*16 + o2 + 1] = a1;
    if (lane < 16) {
      float s = 0.f;
      #pragma unroll
      for (int i = 0; i < 16; ++i) s += hbS[wl][i] * bs2[i*16 + lane];
      hbS[wl][16 + lane] = s;
    }
    __builtin_amdgcn_wave_barrier();
    const float4 mb = *reinterpret_cast<const float4*>(&hbS[wl][16 + q*4]);
    for (int j0 = 0; j0 < deg; j0 += 16) {
      const int jj = j0 + el;
      const bool act = (jj < deg);
      const int slot = st + (act ? jj : 0);
      const int e = elist[slot];
      const int pe = posl[slot];
      const float4 ea0 = *reinterpret_cast<const float4*>(&ea[(size_t)e*8]);
      const float4 ea1 = *reinterpret_cast<const float4*>(&ea[(size_t)e*8 + 4]);
      const float ef[8] = {ea0.x, ea0.y, ea0.z, ea0.w, ea1.x, ea1.y, ea1.z, ea1.w};
      float4 m = mb;
      #pragma unroll
      for (int ff = 0; ff < 8; ++ff) {
        const float4 hv = *reinterpret_cast<const float4*>(&hwS[wl][ff*16 + q*4]);
        m.x += ef[ff]*hv.x; m.y += ef[ff]*hv.y; m.z += ef[ff]*hv.z; m.w += ef[ff]*hv.w;
      }
      if (act)
        *reinterpret_cast<float4*>(&msg[(size_t)pe*16 + q*4]) = m;
      __builtin_amdgcn_wave_barrier();
    }
  }
}

// ---------------- K7: reduce msg + bn1(h1)@root2 + bias2; BN2 stats + raw pooling ----------------
#define PB 98   // nodes per block; 256*98 = 25088 >= 25000
__global__ __launch_bounds__(256) void k7_node2(const float* __restrict__ h1,
    const float* __restrict__ root2, const float* __restrict__ bias2,
    const float* __restrict__ msg, const int* __restrict__ cscoff,
    const int* __restrict__ batch, float* __restrict__ stats) {
  __shared__ float rt[256];
  __shared__ float red[2][16][17];
  __shared__ float sc[16], sh[16];
  __shared__ float pool[64*17];   // [g*17 + o], col 16 = count
  rt[threadIdx.x] = root2[threadIdx.x];
  if (threadIdx.x < 16) { sc[threadIdx.x] = stats[32+threadIdx.x]; sh[threadIdx.x] = stats[48+threadIdx.x]; }
  for (int idx = threadIdx.x; idx < 64*17; idx += 256) pool[idx] = 0.f;
  const int o = threadIdx.x & 15, nl = threadIdx.x >> 4;
  const float bo = bias2[o];
  const int nstart = blockIdx.x * PB;
  const int nend = (nstart + PB < NN) ? nstart + PB : NN;
  float s1 = 0.f, s2 = 0.f;
  __syncthreads();
  for (int n = nstart + nl; n < nend; n += 16) {
    const int b0 = cscoff[n];
    const int deg = cscoff[n+1] - b0;
    float sm = 0.f;
    for (int j = 0; j < deg; ++j) sm += msg[(size_t)(b0 + j)*16 + o];
    float acc = bo;
    #pragma unroll
    for (int i = 0; i < 16; ++i) {
      const float hbn = h1[(size_t)n*16 + i]*sc[i] + sh[i];
      acc += hbn * rt[i*16 + o];
    }
    acc += sm / (float)((deg > 0) ? deg : 1);
    s1 += acc; s2 += acc*acc;
    const int g = batch[n];
    atomicAdd(&pool[g*17 + o], acc);
    if (o == 0) atomicAdd(&pool[g*17 + 16], 1.0f);
  }
  red[0][nl][o] = s1; red[1][nl][o] = s2;
  __syncthreads();
  for (int step = 8; step > 0; step >>= 1) {
    if (nl < step) {
      red[0][nl][o] += red[0][nl+step][o];
      red[1][nl][o] += red[1][nl+step][o];
    }
    __syncthreads();
  }
  if (nl == 0) { atomAddF(&stats[64+o], red[0][0][o]); atomAddF(&stats[80+o], red[1][0][o]); }
  for (int idx = threadIdx.x; idx < 64*17; idx += 256) {
    const float v = pool[idx];
    if (v != 0.f) {
      const int g = idx / 17, c = idx - g*17;
      atomAddF((c < 16) ? &stats[128 + g*16 + c] : &stats[1152 + g], v);
    }
  }
}

__global__ void k8_fin2(const float* __restrict__ g, const float* __restrict__ b,
                        float* __restrict__ stats) {
  const int o = threadIdx.x;
  if (o < 16) {
    const float mean = stats[64+o] / (float)NN;
    const float var  = stats[80+o] / (float)NN - mean*mean;
    const float sc   = g[o] * rsqrtf(var + EPS);
    stats[96+o]  = sc;
    stats[112+o] = b[o] - mean*sc;
  }
}

// ---------------- K10: graph mean (raw) -> BN2 affine -> MLP head -> log_softmax ----------------
__global__ __launch_bounds__(128) void k10_head(const float* __restrict__ stats,
    const float* __restrict__ w1, const float* __restrict__ b1,
    const float* __restrict__ w2, const float* __restrict__ b2,
    float* __restrict__ out) {
  __shared__ float gm[16];
  __shared__ float a[128];
  __shared__ float l[10];
  __shared__ float mls[2];
  const int g = blockIdx.x, j = threadIdx.x;
  if (j < 16) {
    const float cnt = fmaxf(stats[1152 + g], 1.0f);
    gm[j] = (stats[128 + g*16 + j] / cnt) * stats[96 + j] + stats[112 + j];
  }
  __syncthreads();
  float s = b1[j];
  #pragma unroll
  for (int o = 0; o < 16; ++o) s += gm[o]*w1[o*128 + j];
  a[j] = fmaxf(s, 0.f);
  __syncthreads();
  if (j < 10) {
    float t = b2[j];
    #pragma unroll 16
    for (int k = 0; k < 128; ++k) t += a[k]*w2[k*10 + j];
    l[j] = t;
  }
  __syncthreads();
  if (j == 0) {
    float m = l[0];
    for (int c = 1; c < 10; ++c) m = fmaxf(m, l[c]);
    float se = 0.f;
    for (int c = 0; c < 10; ++c) se += expf(l[c]-m);
    mls[0] = m; mls[1] = logf(se);
  }
  __syncthreads();
  if (j < 10) out[g*10 + j] = l[j] - mls[0] - mls[1];
}

extern "C" void kernel_launch(void* const* d_in, const int* in_sizes, int n_in,
                              void* d_out, int out_size, void* d_ws, size_t ws_size,
                              hipStream_t stream) {
  const float* x      = (const float*)d_in[0];
  const int*   esrc   = (const int*)  d_in[1];
  const int*   edst   = (const int*)  d_in[2];
  const float* ea     = (const float*)d_in[3];
  const int*   batch  = (const int*)  d_in[4];
  const float* en1_w1 = (const float*)d_in[5];
  const float* en1_b1 = (const float*)d_in[6];
  const float* en1_w2 = (const float*)d_in[7];
  const float* en1_b2 = (const float*)d_in[8];
  const float* root1  = (const float*)d_in[9];
  const float* bias1  = (const float*)d_in[10];
  const float* bn1_g  = (const float*)d_in[11];
  const float* bn1_b  = (const float*)d_in[12];
  const float* en2_w  = (const float*)d_in[13];
  const float* en2_b  = (const float*)d_in[14];
  const float* root2  = (const float*)d_in[15];
  const float* bias2  = (const float*)d_in[16];
  const float* bn2_g  = (const float*)d_in[17];
  const float* bn2_b  = (const float*)d_in[18];
  const float* mlp_w1 = (const float*)d_in[19];
  const float* mlp_b1 = (const float*)d_in[20];
  const float* mlp_w2 = (const float*)d_in[21];
  const float* mlp_b2 = (const float*)d_in[22];
  float* out = (float*)d_out;
  float* ws  = (float*)d_ws;

  float* xwbuf  = ws + OFS_XWBUF;
  float* xb2    = ws + OFS_XB2;
  float* msg    = ws + OFS_MSG;
  float* stats  = ws + OFS_STATS;
  float* h1     = ws + OFS_H1;
  int*   elist  = (int*)(ws + OFS_ELIST);
  int*   posl   = (int*)(ws + OFS_POSL);
  int*   off    = (int*)(ws + OFS_OFF);
  int*   cscoff = (int*)(ws + OFS_CSCOFF);
  int*   outc   = (int*)(ws + OFS_OUTC);
  int*   inc    = (int*)(ws + OFS_INC);
  int*   bsum   = (int*)(ws + OFS_BSUM);

  hipMemsetAsync(outc,  0, 25600*sizeof(int), stream);
  hipMemsetAsync(inc,   0, 25600*sizeof(int), stream);
  hipMemsetAsync(stats, 0, 2048*sizeof(float), stream);

  // CSR + CSC build (multi-block scan)
  hipLaunchKernelGGL(k0_hist,  dim3(1024), dim3(256), 0, stream, esrc, edst, outc, inc);
  hipLaunchKernelGGL(k0_scanA, dim3(100),  dim3(256), 0, stream, outc, inc, bsum);
  hipLaunchKernelGGL(k0_scanB, dim3(1),    dim3(128), 0, stream, bsum);
  hipLaunchKernelGGL(k0_scanC, dim3(100),  dim3(256), 0, stream, outc, inc, bsum, off, cscoff);
  hipLaunchKernelGGL(k0_fill,  dim3(1024), dim3(256), 0, stream, esrc, edst, outc, inc,
                     off, cscoff, elist, posl);

  // layer 1, chunked over nodes
  const int nb1 = (CHUNK + 15) / 16;
  hipLaunchKernelGGL(k1_xw,  dim3(nb1),  dim3(256), 0, stream, x, en1_w2, en1_b2, xwbuf, xb2, 0, CHUNK);
  hipLaunchKernelGGL(k2_csr, dim3(1024), dim3(256), 0, stream, ea, en1_w1, en1_b1,
                     xwbuf, xb2, off, elist, posl, msg, 0, CHUNK);
  hipLaunchKernelGGL(k1_xw,  dim3(nb1),  dim3(256), 0, stream, x, en1_w2, en1_b2, xwbuf, xb2, CHUNK, NN);
  hipLaunchKernelGGL(k2_csr, dim3(1024), dim3(256), 0, stream, ea, en1_w1, en1_b1,
                     xwbuf, xb2, off, elist, posl, msg, CHUNK, NN);

  hipLaunchKernelGGL(k3_node1, dim3(256), dim3(256), 0, stream, x, root1, bias1, msg, cscoff, h1, stats);
  hipLaunchKernelGGL(k4_fin1,  dim3(1),   dim3(64),  0, stream, bn1_g, bn1_b, stats);

  // layer 2
  hipLaunchKernelGGL(k6_csr,   dim3(1024), dim3(256), 0, stream, ea, h1, stats,
                     en2_w, en2_b, off, elist, posl, msg);
  hipLaunchKernelGGL(k7_node2, dim3(256),  dim3(256), 0, stream, h1, root2, bias2, msg, cscoff,
                     batch, stats);
  hipLaunchKernelGGL(k8_fin2,  dim3(1),    dim3(64),  0, stream, bn2_g, bn2_b, stats);

  // head
  hipLaunchKernelGGL(k10_head, dim3(64),  dim3(128), 0, stream, stats, mlp_w1, mlp_b1, mlp_w2, mlp_b2, out);
}